// Round 5
// baseline (641.423 us; speedup 1.0000x reference)
//
#include <hip/hip_runtime.h>

// Problem constants: B=4, N=4096 -> nPoints=16384
#define KN 32                 // neighbors per point
#define FF 64                 // input feature dim
#define CC 256                // H*D channels (H=16 heads, D=16)
#define NITER 16              // points per block
#define KVST 36               // bf16 elems per kvT row: 32 neighbor cols + 4 pad (x18 dwords -> <=2-way banks)
#define QST 257               // u16 per qAll row
#define WST 34                // floats per wS2 head row (16 float2 pairs + 1 pad pair = 136 B)

// Faithful-reshape semantics (validated R1-R3):
//   K[b,n,h,k,d] = K_proj[b,n, j=2h+(k>>4), ch=(k&15)*16+d];  V likewise.
//   Q[b,n,h,0,d] = Q_proj[b,n, h*16+d].
// New attention ownership (kvT layout): lane (h,d) owns k=d (j=2h) and
// k=16+d (j=2h+1); one b32 read of kvT[ch][2h..2h+1] feeds both.

typedef __attribute__((ext_vector_type(8)))  short bf16x8;   // 8 bf16 = 4 VGPRs
typedef __attribute__((ext_vector_type(16))) float f32x16;   // 32x32 MFMA acc
typedef __attribute__((ext_vector_type(4)))  float f32x4;    // 16x16 MFMA acc

// round-half-up fp32->bf16 pack: 3 VALU (2 add + v_perm)
__device__ inline unsigned pack2ru(float a, float b) {
    unsigned au = __float_as_uint(a) + 0x8000u;
    unsigned bu = __float_as_uint(b) + 0x8000u;
    return __builtin_amdgcn_perm(bu, au, 0x07060302u);  // [a.hi16, b.hi16]
}
__device__ inline unsigned short f2bf_ru(float a) {
    return (unsigned short)((__float_as_uint(a) + 0x8000u) >> 16);
}
__device__ inline bf16x8 pack8(float4 a, float4 b) {
    union { bf16x8 v; unsigned u[4]; } r;
    r.u[0] = pack2ru(a.x, a.y);  r.u[1] = pack2ru(a.z, a.w);
    r.u[2] = pack2ru(b.x, b.y);  r.u[3] = pack2ru(b.z, b.w);
    return r.v;
}
__device__ inline float bflo(unsigned u) { return __uint_as_float(u << 16); }
__device__ inline float bfhi(unsigned u) { return __uint_as_float(u & 0xffff0000u); }

__global__ __launch_bounds__(256, 3)
void attn_one(const float* __restrict__ inp,
              const float* __restrict__ query,
              const float* __restrict__ Wq,
              const float* __restrict__ bq,
              const float* __restrict__ Wk,
              const float* __restrict__ bk,
              const float* __restrict__ Wv,
              const float* __restrict__ bv,
              float* __restrict__ out, int nPoints)
{
    // 47.3 KB total -> 3 blocks/CU
    __shared__ __align__(16) unsigned short kvT[512 * KVST];  // 36864 B: K rows 0..255, V rows 256..511
    __shared__ unsigned short qAll[NITER * QST];              // 8224 B: pre-scaled Q, bf16
    __shared__ float wS2[16 * WST];                           // 2176 B: per-head (w[m], w[m+16]) pairs

    const int tid  = threadIdx.x;
    const int wave = tid >> 6;
    const int L    = tid & 63;
    const int Lm   = L & 31;       // M/N index in 32x32 tile
    const int Lh   = L >> 5;       // k-half selector
    const int h    = tid >> 4;     // attention head 0..15 (intra-wave: 4 heads/wave)
    const int d    = tid & 15;     // dim within head
    const int bid  = blockIdx.x;
    const int grid = gridDim.x;

    // ---- prefetch first point's A-row immediately (hide behind whole prologue) ----
    float4 pf[8];
    {
        const float* arow = inp + (size_t)bid * (KN * FF) + Lm * FF + Lh * 8;
#pragma unroll
        for (int s = 0; s < 4; ++s) {
            pf[2 * s]     = *(const float4*)(arow + s * 16);
            pf[2 * s + 1] = *(const float4*)(arow + s * 16 + 4);
        }
    }

    // ---- stage this block's 16 query rows into kvT scratch (freed at loop) ----
    float* qIn = (float*)kvT;      // 16 rows x 68 floats
    {
        const int i  = tid >> 4;
        const int f4 = (tid & 15) * 4;
        const int p  = bid + i * grid;
        if (p < nPoints)
            *(float4*)(qIn + i * 68 + f4) =
                *(const float4*)(query + (size_t)p * FF + f4);
    }

    // ---- Wk/Wv B fragments + bias (validated R2/R3 layout) ----
    bf16x8 Bf[4][4];   // [tile: K0,K1,V0,V1][kstep]
    float  bias[4];
#pragma unroll
    for (int t = 0; t < 4; ++t) {
        const float* W  = (t < 2) ? Wk : Wv;
        const float* bb = (t < 2) ? bk : bv;
        const int ch    = (2 * wave + (t & 1)) * 32 + Lm;
        bias[t] = bb[ch];
#pragma unroll
        for (int s = 0; s < 4; ++s) {
            union { bf16x8 v; unsigned u[4]; } r;
#pragma unroll
            for (int jj = 0; jj < 4; ++jj) {
                const int f = s * 16 + Lh * 8 + 2 * jj;
                r.u[jj] = pack2ru(W[(size_t)f * CC + ch], W[(size_t)(f + 1) * CC + ch]);
            }
            Bf[t][s] = r.v;
        }
    }

    // ---- Wq B fragments (validated R3) ----
    const int nq = L & 15;
    const int kq = (L >> 4) * 8;
    {
        bf16x8 Bq[4][2];
        float  bqv[4];
#pragma unroll
        for (int tt = 0; tt < 4; ++tt) {
            const int ch = wave * 64 + tt * 16 + nq;
            bqv[tt] = bq[ch];
#pragma unroll
            for (int s = 0; s < 2; ++s) {
                union { bf16x8 v; unsigned u[4]; } r;
#pragma unroll
                for (int jj = 0; jj < 4; ++jj) {
                    const int f = s * 32 + kq + 2 * jj;
                    r.u[jj] = pack2ru(Wq[(size_t)f * CC + ch], Wq[(size_t)(f + 1) * CC + ch]);
                }
                Bq[tt][s] = r.v;
            }
        }
        __syncthreads();   // qIn staged

        // ---- Q-projection MFMA: M=16 points, N=256, K=64 (validated R3) ----
        bf16x8 Aq[2];
        const int im = L & 15;
#pragma unroll
        for (int s = 0; s < 2; ++s) {
            const float* qr = qIn + im * 68 + s * 32 + kq;
            Aq[s] = pack8(*(const float4*)qr, *(const float4*)(qr + 4));
        }
#pragma unroll
        for (int tt = 0; tt < 4; ++tt) {
            f32x4 qa = {0.f, 0.f, 0.f, 0.f};
#pragma unroll
            for (int s = 0; s < 2; ++s)
                qa = __builtin_amdgcn_mfma_f32_16x16x32_bf16(Aq[s], Bq[tt][s], qa, 0, 0, 0);
            const int ch = wave * 64 + tt * 16 + nq;
#pragma unroll
            for (int r = 0; r < 4; ++r) {
                const int ip = (L >> 4) * 4 + r;
                qAll[ip * QST + ch] = f2bf_ru((qa[r] + bqv[tt]) * 0.25f);  // pre-scaled 1/sqrt(16)
            }
        }
    }
    // qAll is wave-private (wave w writes/reads channels [64w,64w+64)); the
    // loop-top __syncthreads orders qIn-scratch reuse.

    // ================= main loop =================
    for (int it = 0, p = bid; it < NITER && p < nPoints; ++it, p += grid) {
        // A-pack + MFMA (acc initialized with bias; pf dies here)
        f32x16 acc[4];
#pragma unroll
        for (int t = 0; t < 4; ++t)
#pragma unroll
            for (int r = 0; r < 16; ++r) acc[t][r] = bias[t];
#pragma unroll
        for (int s = 0; s < 4; ++s) {
            bf16x8 Af = pack8(pf[2 * s], pf[2 * s + 1]);   // A[m=Lm][k=s*16+Lh*8+j]
#pragma unroll
            for (int t = 0; t < 4; ++t)
                acc[t] = __builtin_amdgcn_mfma_f32_32x32x16_bf16(Af, Bf[t][s], acc[t], 0, 0, 0);
        }

        __syncthreads();   // A: previous point's attention reads done

        // ---- writeback -> kvT (bf16, transposed): 16 x ds_write_b64 ----
#pragma unroll
        for (int t = 0; t < 4; ++t) {
            const int row = ((t < 2) ? 0 : 256) + (2 * wave + (t & 1)) * 32 + Lm;
#pragma unroll
            for (int rg = 0; rg < 4; ++rg) {
                const int jb = 8 * rg + 4 * Lh;           // 4 consecutive neighbors
                uint2 w2;
                w2.x = pack2ru(acc[t][4 * rg + 0], acc[t][4 * rg + 1]);
                w2.y = pack2ru(acc[t][4 * rg + 2], acc[t][4 * rg + 3]);
                *(uint2*)(kvT + row * KVST + jb) = w2;
            }
        }

        __syncthreads();   // B: kvT ready

        // ---- prefetch next point's A-row (acc dead; lives through attention) ----
        const int pn = p + grid;
        if (pn < nPoints) {
            const float* arow = inp + (size_t)pn * (KN * FF) + Lm * FF + Lh * 8;
#pragma unroll
            for (int s = 0; s < 4; ++s) {
                pf[2 * s]     = *(const float4*)(arow + s * 16);
                pf[2 * s + 1] = *(const float4*)(arow + s * 16 + 4);
            }
        }

        // ---- logits: lane (h,d) owns k=d (j=2h) and k=16+d (j=2h+1) ----
        const unsigned short* qrow = qAll + it * QST + h * 16;
        float l0 = 0.f, l1 = 0.f;
#pragma unroll
        for (int i = 0; i < 16; ++i) {
            const int dp = (d + i) & 15;                  // rotation: banks spread (<=2-way)
            const unsigned kk = *(const unsigned*)(kvT + (16 * d + dp) * KVST + 2 * h);
            const float qv = bflo((unsigned)qrow[dp]);
            l0 = fmaf(qv, bflo(kk), l0);
            l1 = fmaf(qv, bfhi(kk), l1);
        }

        // ---- softmax across the head's 16 lanes (32 logits total) ----
        float m = fmaxf(l0, l1);
        m = fmaxf(m, __shfl_xor(m, 1));
        m = fmaxf(m, __shfl_xor(m, 2));
        m = fmaxf(m, __shfl_xor(m, 4));
        m = fmaxf(m, __shfl_xor(m, 8));
        float e0 = __expf(l0 - m), e1 = __expf(l1 - m);
        float s2 = e0 + e1;
        s2 += __shfl_xor(s2, 1);
        s2 += __shfl_xor(s2, 2);
        s2 += __shfl_xor(s2, 4);
        s2 += __shfl_xor(s2, 8);
        const float inv = 1.0f / s2;
        *(float2*)(wS2 + h * WST + 2 * d) = make_float2(e0 * inv, e1 * inv);
        __builtin_amdgcn_wave_barrier();   // wS2 is intra-wave (same head's lanes)

        // ---- output: one b32 V-read covers both neighbors per channel group ----
        float o = 0.f;
#pragma unroll
        for (int mm = 0; mm < 16; ++mm) {
            const unsigned vv = *(const unsigned*)(kvT + (256 + 16 * mm + d) * KVST + 2 * h);
            const float2 w = *(const float2*)(wS2 + h * WST + 2 * mm);  // broadcast
            o = fmaf(w.x, bflo(vv), o);
            o = fmaf(w.y, bfhi(vv), o);
        }
        out[(size_t)p * CC + tid] = o;
        // next iteration's barrier A orders kvT/wS2 reuse
    }
}

extern "C" void kernel_launch(void* const* d_in, const int* in_sizes, int n_in,
                              void* d_out, int out_size, void* d_ws, size_t ws_size,
                              hipStream_t stream) {
    const float* inp   = (const float*)d_in[0];
    const float* query = (const float*)d_in[1];
    const float* Wq    = (const float*)d_in[2];
    const float* bq    = (const float*)d_in[3];
    const float* Wk    = (const float*)d_in[4];
    const float* bk    = (const float*)d_in[5];
    const float* Wv    = (const float*)d_in[6];
    const float* bv    = (const float*)d_in[7];
    float* out = (float*)d_out;

    const int nPoints = in_sizes[0] / (KN * FF);          // 16384
    const int grid    = (nPoints + NITER - 1) / NITER;    // 1024

    attn_one<<<grid, 256, 0, stream>>>(inp, query, Wq, bq, Wk, bk, Wv, bv,
                                       out, nPoints);
}

// Round 6
// 305.416 us; speedup vs baseline: 2.1002x; 2.1002x over previous
//
#include <hip/hip_runtime.h>

// Problem constants: B=4, N=4096 -> nPoints=16384
#define KN 32                 // neighbors per point
#define FF 64                 // input feature dim
#define CC 256                // H*D channels (H=16 heads, D=16)
#define NITER 16              // points per block
#define KVST 36               // bf16 elems per kvT row: 32 neighbor cols + 4 pad (x18 dwords -> <=2-way banks)
#define QST 257               // u16 per qAll row
#define WST 34                // floats per wS2 head row (16 float2 pairs + 1 pad pair = 136 B)

// Faithful-reshape semantics (validated R1-R4):
//   K[b,n,h,k,d] = K_proj[b,n, j=2h+(k>>4), ch=(k&15)*16+d];  V likewise.
//   Q[b,n,h,0,d] = Q_proj[b,n, h*16+d].
// kvT layout (validated R4: conflicts 8.4M -> 196K): lane (h,d) owns k=d
// (j=2h) and k=16+d (j=2h+1); one b32 read of kvT[ch][2h..2h+1] feeds both.

typedef __attribute__((ext_vector_type(8)))  short bf16x8;   // 8 bf16 = 4 VGPRs
typedef __attribute__((ext_vector_type(16))) float f32x16;   // 32x32 MFMA acc
typedef __attribute__((ext_vector_type(4)))  float f32x4;    // 16x16 MFMA acc

// round-half-up fp32->bf16 pack: 3 VALU (2 add + v_perm)
__device__ inline unsigned pack2ru(float a, float b) {
    unsigned au = __float_as_uint(a) + 0x8000u;
    unsigned bu = __float_as_uint(b) + 0x8000u;
    return __builtin_amdgcn_perm(bu, au, 0x07060302u);  // [a.hi16, b.hi16]
}
__device__ inline unsigned short f2bf_ru(float a) {
    return (unsigned short)((__float_as_uint(a) + 0x8000u) >> 16);
}
__device__ inline bf16x8 pack8(float4 a, float4 b) {
    union { bf16x8 v; unsigned u[4]; } r;
    r.u[0] = pack2ru(a.x, a.y);  r.u[1] = pack2ru(a.z, a.w);
    r.u[2] = pack2ru(b.x, b.y);  r.u[3] = pack2ru(b.z, b.w);
    return r.v;
}
__device__ inline float bflo(unsigned u) { return __uint_as_float(u << 16); }
__device__ inline float bfhi(unsigned u) { return __uint_as_float(u & 0xffff0000u); }

// launch_bounds(256,2): R4's (256,3) capped regs at ~170 < ~185 live set ->
// scratch spills (VGPR=84, +880 MB HBM). 2 waves/EU gives 256 regs/wave.
__global__ __launch_bounds__(256, 2)
void attn_one(const float* __restrict__ inp,
              const float* __restrict__ query,
              const float* __restrict__ Wq,
              const float* __restrict__ bq,
              const float* __restrict__ Wk,
              const float* __restrict__ bk,
              const float* __restrict__ Wv,
              const float* __restrict__ bv,
              float* __restrict__ out, int nPoints)
{
    __shared__ __align__(16) unsigned short kvT[512 * KVST];  // 36864 B: K rows 0..255, V rows 256..511
    __shared__ unsigned short qAll[NITER * QST];              // 8224 B: pre-scaled Q, bf16
    __shared__ float wS2[16 * WST];                           // 2176 B: per-head (w[m], w[m+16]) pairs

    const int tid  = threadIdx.x;
    const int wave = tid >> 6;
    const int L    = tid & 63;
    const int Lm   = L & 31;       // M/N index in 32x32 tile
    const int Lh   = L >> 5;       // k-half selector
    const int h    = tid >> 4;     // attention head 0..15 (intra-wave: 4 heads/wave)
    const int d    = tid & 15;     // dim within head
    const int bid  = blockIdx.x;
    const int grid = gridDim.x;

    // ---- prefetch first point's A-row immediately (hide behind whole prologue) ----
    float4 pf[8];
    {
        const float* arow = inp + (size_t)bid * (KN * FF) + Lm * FF + Lh * 8;
#pragma unroll
        for (int s = 0; s < 4; ++s) {
            pf[2 * s]     = *(const float4*)(arow + s * 16);
            pf[2 * s + 1] = *(const float4*)(arow + s * 16 + 4);
        }
    }

    // ---- stage this block's 16 query rows into kvT scratch (freed at loop) ----
    float* qIn = (float*)kvT;      // 16 rows x 68 floats
    {
        const int i  = tid >> 4;
        const int f4 = (tid & 15) * 4;
        const int p  = bid + i * grid;
        if (p < nPoints)
            *(float4*)(qIn + i * 68 + f4) =
                *(const float4*)(query + (size_t)p * FF + f4);
    }

    // ---- Wk/Wv B fragments + bias (validated R2/R3 layout) ----
    bf16x8 Bf[4][4];   // [tile: K0,K1,V0,V1][kstep]
    float  bias[4];
#pragma unroll
    for (int t = 0; t < 4; ++t) {
        const float* W  = (t < 2) ? Wk : Wv;
        const float* bb = (t < 2) ? bk : bv;
        const int ch    = (2 * wave + (t & 1)) * 32 + Lm;
        bias[t] = bb[ch];
#pragma unroll
        for (int s = 0; s < 4; ++s) {
            union { bf16x8 v; unsigned u[4]; } r;
#pragma unroll
            for (int jj = 0; jj < 4; ++jj) {
                const int f = s * 16 + Lh * 8 + 2 * jj;
                r.u[jj] = pack2ru(W[(size_t)f * CC + ch], W[(size_t)(f + 1) * CC + ch]);
            }
            Bf[t][s] = r.v;
        }
    }

    // ---- Wq B fragments (validated R3) ----
    const int nq = L & 15;
    const int kq = (L >> 4) * 8;
    {
        bf16x8 Bq[4][2];
        float  bqv[4];
#pragma unroll
        for (int tt = 0; tt < 4; ++tt) {
            const int ch = wave * 64 + tt * 16 + nq;
            bqv[tt] = bq[ch];
#pragma unroll
            for (int s = 0; s < 2; ++s) {
                union { bf16x8 v; unsigned u[4]; } r;
#pragma unroll
                for (int jj = 0; jj < 4; ++jj) {
                    const int f = s * 32 + kq + 2 * jj;
                    r.u[jj] = pack2ru(Wq[(size_t)f * CC + ch], Wq[(size_t)(f + 1) * CC + ch]);
                }
                Bq[tt][s] = r.v;
            }
        }
        __syncthreads();   // qIn staged

        // ---- Q-projection MFMA: M=16 points, N=256, K=64 (validated R3) ----
        bf16x8 Aq[2];
        const int im = L & 15;
#pragma unroll
        for (int s = 0; s < 2; ++s) {
            const float* qr = qIn + im * 68 + s * 32 + kq;
            Aq[s] = pack8(*(const float4*)qr, *(const float4*)(qr + 4));
        }
#pragma unroll
        for (int tt = 0; tt < 4; ++tt) {
            f32x4 qa = {0.f, 0.f, 0.f, 0.f};
#pragma unroll
            for (int s = 0; s < 2; ++s)
                qa = __builtin_amdgcn_mfma_f32_16x16x32_bf16(Aq[s], Bq[tt][s], qa, 0, 0, 0);
            const int ch = wave * 64 + tt * 16 + nq;
#pragma unroll
            for (int r = 0; r < 4; ++r) {
                const int ip = (L >> 4) * 4 + r;
                qAll[ip * QST + ch] = f2bf_ru((qa[r] + bqv[tt]) * 0.25f);  // pre-scaled 1/sqrt(16)
            }
        }
    }
    // qAll is wave-private (wave w writes/reads channels [64w,64w+64)); the
    // loop-top __syncthreads orders qIn-scratch reuse.

    // ================= main loop =================
    for (int it = 0, p = bid; it < NITER && p < nPoints; ++it, p += grid) {
        // A-pack + MFMA (acc initialized with bias; pf dies here)
        f32x16 acc[4];
#pragma unroll
        for (int t = 0; t < 4; ++t)
#pragma unroll
            for (int r = 0; r < 16; ++r) acc[t][r] = bias[t];
#pragma unroll
        for (int s = 0; s < 4; ++s) {
            bf16x8 Af = pack8(pf[2 * s], pf[2 * s + 1]);   // A[m=Lm][k=s*16+Lh*8+j]
#pragma unroll
            for (int t = 0; t < 4; ++t)
                acc[t] = __builtin_amdgcn_mfma_f32_32x32x16_bf16(Af, Bf[t][s], acc[t], 0, 0, 0);
        }

        __syncthreads();   // A: previous point's attention reads done

        // ---- writeback -> kvT (bf16, transposed): 16 x ds_write_b64 ----
#pragma unroll
        for (int t = 0; t < 4; ++t) {
            const int row = ((t < 2) ? 0 : 256) + (2 * wave + (t & 1)) * 32 + Lm;
#pragma unroll
            for (int rg = 0; rg < 4; ++rg) {
                const int jb = 8 * rg + 4 * Lh;           // 4 consecutive neighbors
                uint2 w2;
                w2.x = pack2ru(acc[t][4 * rg + 0], acc[t][4 * rg + 1]);
                w2.y = pack2ru(acc[t][4 * rg + 2], acc[t][4 * rg + 3]);
                *(uint2*)(kvT + row * KVST + jb) = w2;
            }
        }

        __syncthreads();   // B: kvT ready

        // ---- prefetch next point's A-row (acc dead; lives through attention) ----
        const int pn = p + grid;
        if (pn < nPoints) {
            const float* arow = inp + (size_t)pn * (KN * FF) + Lm * FF + Lh * 8;
#pragma unroll
            for (int s = 0; s < 4; ++s) {
                pf[2 * s]     = *(const float4*)(arow + s * 16);
                pf[2 * s + 1] = *(const float4*)(arow + s * 16 + 4);
            }
        }

        // ---- logits: lane (h,d) owns k=d (j=2h) and k=16+d (j=2h+1) ----
        const unsigned short* qrow = qAll + it * QST + h * 16;
        float l0 = 0.f, l1 = 0.f;
#pragma unroll
        for (int i = 0; i < 16; ++i) {
            const int dp = (d + i) & 15;                  // rotation: banks spread (<=2-way)
            const unsigned kk = *(const unsigned*)(kvT + (16 * d + dp) * KVST + 2 * h);
            const float qv = bflo((unsigned)qrow[dp]);
            l0 = fmaf(qv, bflo(kk), l0);
            l1 = fmaf(qv, bfhi(kk), l1);
        }

        // ---- softmax across the head's 16 lanes (32 logits total) ----
        float m = fmaxf(l0, l1);
        m = fmaxf(m, __shfl_xor(m, 1));
        m = fmaxf(m, __shfl_xor(m, 2));
        m = fmaxf(m, __shfl_xor(m, 4));
        m = fmaxf(m, __shfl_xor(m, 8));
        float e0 = __expf(l0 - m), e1 = __expf(l1 - m);
        float s2 = e0 + e1;
        s2 += __shfl_xor(s2, 1);
        s2 += __shfl_xor(s2, 2);
        s2 += __shfl_xor(s2, 4);
        s2 += __shfl_xor(s2, 8);
        const float inv = 1.0f / s2;
        *(float2*)(wS2 + h * WST + 2 * d) = make_float2(e0 * inv, e1 * inv);
        __builtin_amdgcn_wave_barrier();   // wS2 is intra-wave (same head's lanes)

        // ---- output: one b32 V-read covers both neighbors per channel group ----
        float o = 0.f;
#pragma unroll
        for (int mm = 0; mm < 16; ++mm) {
            const unsigned vv = *(const unsigned*)(kvT + (256 + 16 * mm + d) * KVST + 2 * h);
            const float2 w = *(const float2*)(wS2 + h * WST + 2 * mm);  // broadcast
            o = fmaf(w.x, bflo(vv), o);
            o = fmaf(w.y, bfhi(vv), o);
        }
        out[(size_t)p * CC + tid] = o;
        // next iteration's barrier A orders kvT/wS2 reuse
    }
}

extern "C" void kernel_launch(void* const* d_in, const int* in_sizes, int n_in,
                              void* d_out, int out_size, void* d_ws, size_t ws_size,
                              hipStream_t stream) {
    const float* inp   = (const float*)d_in[0];
    const float* query = (const float*)d_in[1];
    const float* Wq    = (const float*)d_in[2];
    const float* bq    = (const float*)d_in[3];
    const float* Wk    = (const float*)d_in[4];
    const float* bk    = (const float*)d_in[5];
    const float* Wv    = (const float*)d_in[6];
    const float* bv    = (const float*)d_in[7];
    float* out = (float*)d_out;

    const int nPoints = in_sizes[0] / (KN * FF);          // 16384
    const int grid    = (nPoints + NITER - 1) / NITER;    // 1024

    attn_one<<<grid, 256, 0, stream>>>(inp, query, Wq, bq, Wk, bk, Wv, bv,
                                       out, nPoints);
}